// Round 1
// baseline (701.301 us; speedup 1.0000x reference)
//
#include <hip/hip_runtime.h>
#include <hip/hip_bf16.h>
#include <stdint.h>

// ---------------------------------------------------------------------------
// FiBiNet forward, MI355X (gfx950).  R3: fc0 GEMM rebuilt as double-buffered
// counted-vmcnt pipeline (T3+T4+T5): 256x128 tile, 512 thr (8 waves 2Mx4N),
// both operands staged via global_load_lds (B stays fp32, cvt_pk on consume),
// raw s_barrier + s_waitcnt vmcnt(4) so prefetch loads stay in flight across
// barriers.  splitK 16->8 (halves partial traffic).  Everything else as R2.
// ---------------------------------------------------------------------------

typedef __attribute__((ext_vector_type(4))) int   int4v;
typedef __attribute__((ext_vector_type(4))) unsigned uint4v;
typedef __attribute__((ext_vector_type(4))) float f32x4;

__device__ __forceinline__ unsigned short f32_bf16(float f) {
  unsigned u = __builtin_bit_cast(unsigned, f);
  u = (u + 0x7fffu + ((u >> 16) & 1u)) >> 16;   // RNE
  return (unsigned short)u;
}
__device__ __forceinline__ unsigned pk_bf16(float lo, float hi) {
  return (unsigned)f32_bf16(lo) | ((unsigned)f32_bf16(hi) << 16);
}
__device__ __forceinline__ unsigned cvt_pk(float lo, float hi) {
  unsigned r;
  asm("v_cvt_pk_bf16_f32 %0, %1, %2" : "=v"(r) : "v"(lo), "v"(hi));
  return r;
}

// ------------------------------- SE block ----------------------------------
__global__ __launch_bounds__(256) void se_kernel(
    const float* __restrict__ x, const float* __restrict__ w1,
    const float* __restrict__ w2, float* __restrict__ scale) {
  __shared__ float Z[32];
  __shared__ float A1[4];
  int b = blockIdx.x;
  int t = threadIdx.x;
  int f = t >> 3, sub = t & 7;
  const float4* xp = (const float4*)(x + (size_t)b * 2048 + f * 64 + sub * 8);
  float4 v0 = xp[0], v1 = xp[1];
  float s = v0.x + v0.y + v0.z + v0.w + v1.x + v1.y + v1.z + v1.w;
  s += __shfl_down(s, 4, 8);
  s += __shfl_down(s, 2, 8);
  s += __shfl_down(s, 1, 8);
  if (sub == 0) Z[f] = s * (1.0f / 64.0f);
  __syncthreads();
  if (t < 4) {
    float a = 0.f;
#pragma unroll
    for (int ff = 0; ff < 32; ++ff) a += Z[ff] * w1[t * 32 + ff];
    A1[t] = fmaxf(a, 0.f);
  }
  __syncthreads();
  if (t < 32) {
    float a = 0.f;
#pragma unroll
    for (int r = 0; r < 4; ++r) a += A1[r] * w2[t * 4 + r];
    scale[b * 32 + t] = 1.f / (1.f + expf(-a));
  }
}

// -------------------- per-field bilinear transforms ------------------------
__global__ __launch_bounds__(256) void t_kernel(
    const float* __restrict__ x, const float* __restrict__ W1,
    const float* __restrict__ W2, const float* __restrict__ scale,
    float* __restrict__ t1, float* __restrict__ t2) {
  __shared__ float Wl[64 * 65];
  __shared__ float xs[64 * 65];
  int f = blockIdx.x;
  int b0 = blockIdx.y * 64;
  int which = blockIdx.z;
  const float* W = (which ? W2 : W1) + (size_t)f * 4096;
  float* tout = which ? t2 : t1;
  int t = threadIdx.x;
#pragma unroll
  for (int it = 0; it < 16; ++it) {
    int idx = it * 256 + t;
    int o = idx >> 6, e = idx & 63;
    Wl[o * 65 + e] = W[idx];
  }
#pragma unroll
  for (int it = 0; it < 16; ++it) {
    int idx = it * 256 + t;
    int bl = idx >> 6, e = idx & 63;
    float v = x[(size_t)(b0 + bl) * 2048 + f * 64 + e];
    if (which) v *= scale[(b0 + bl) * 32 + f];
    xs[bl * 65 + e] = v;
  }
  __syncthreads();
  int o = t & 63, g = t >> 6;
  float sum[16];
#pragma unroll
  for (int r = 0; r < 16; ++r) sum[r] = 0.f;
#pragma unroll 4
  for (int e = 0; e < 64; ++e) {
    float wv = Wl[o * 65 + e];
#pragma unroll
    for (int r = 0; r < 16; ++r) sum[r] += xs[(g * 16 + r) * 65 + e] * wv;
  }
#pragma unroll
  for (int r = 0; r < 16; ++r)
    tout[(size_t)(b0 + g * 16 + r) * 1984 + f * 64 + o] = sum[r];
}

// ----------------------- pair feature materialization ----------------------
__global__ __launch_bounds__(256) void feat_kernel(
    const float* __restrict__ x, const float* __restrict__ t1,
    const float* __restrict__ t2, const float* __restrict__ scale,
    unsigned short* __restrict__ feat) {
  int gid = blockIdx.x * 256 + threadIdx.x;
  int b = gid / 7936;
  int rem = gid - b * 7936;
  int s = rem >> 3;
  int e0 = (rem & 7) * 8;
  int which = (s >= 496) ? 1 : 0;
  int p = s - (which ? 496 : 0);
  int i = (int)((63.0f - sqrtf((float)(3969 - 8 * p))) * 0.5f);
  while ((i * (63 - i)) / 2 > p) --i;
  while (((i + 1) * (62 - i)) / 2 <= p) ++i;
  int j = i + 1 + (p - (i * (63 - i)) / 2);
  const float* tp = (which ? t2 : t1) + (size_t)b * 1984 + i * 64 + e0;
  const float* xp = x + (size_t)b * 2048 + j * 64 + e0;
  float sc = which ? scale[b * 32 + j] : 1.0f;
  float4 ta = *(const float4*)tp, tb = *(const float4*)(tp + 4);
  float4 xa = *(const float4*)xp, xb = *(const float4*)(xp + 4);
  uint4v o;
  o.x = pk_bf16(ta.x * xa.x * sc, ta.y * xa.y * sc);
  o.y = pk_bf16(ta.z * xa.z * sc, ta.w * xa.w * sc);
  o.z = pk_bf16(tb.x * xb.x * sc, tb.y * xb.y * sc);
  o.w = pk_bf16(tb.z * xb.z * sc, tb.w * xb.w * sc);
  *(uint4v*)(feat + (size_t)b * 63488 + s * 64 + e0) = o;
}

// ------------------------------- MFMA GEMM ---------------------------------
__device__ __forceinline__ void mfma_bf16(f32x4& d, int4v a, int4v b) {
  asm volatile("v_mfma_f32_16x16x32_bf16 %0, %1, %2, %0"
               : "+v"(d) : "v"(a), "v"(b));
}

// ---- fc0 pipeline GEMM: 256x128 tile, BK=64, 512 thr, dbuf + counted vmcnt.
// A bf16 via global_load_lds, source pre-swizzled: slot p holds chunk
// p ^ (row&7)  (8 chunks of 8 bf16 per row).
// B fp32 via global_load_lds, source pre-swizzled at 16B-chunk granularity:
// slot s holds chunk s ^ (2*(row&7))  (16 chunks of 4 f32 per row); consume
// side reads the contiguous 32B pair at pair-slot (kchunk ^ (row&7)) and
// converts with v_cvt_pk_bf16_f32.
#define FBM 256
#define FBN 128
#define FBK 64

__device__ __forceinline__ void fc0_phase(
    const unsigned short* __restrict__ sAb, const float* __restrict__ sBb,
    int kk, int wr, int wc, int l15, int l4, f32x4 (&acc)[8][2]) {
  int4v av[8];
#pragma unroll
  for (int i = 0; i < 8; ++i) {
    int ar = wr + i * 16 + l15;
    int slot = (kk * 4 + l4) ^ (ar & 7);
    av[i] = *(const int4v*)&sAb[(ar * 8 + slot) * 8];
  }
  int4v bv[2];
#pragma unroll
  for (int j = 0; j < 2; ++j) {
    int br = wc + j * 16 + l15;
    int ps = (kk * 4 + l4) ^ (br & 7);
    const float4* fp = (const float4*)&sBb[br * 64 + ps * 8];
    float4 f0 = fp[0], f1 = fp[1];
    uint4v q;
    q.x = cvt_pk(f0.x, f0.y);
    q.y = cvt_pk(f0.z, f0.w);
    q.z = cvt_pk(f1.x, f1.y);
    q.w = cvt_pk(f1.z, f1.w);
    bv[j] = __builtin_bit_cast(int4v, q);
  }
  __builtin_amdgcn_s_setprio(1);
#pragma unroll
  for (int i = 0; i < 8; ++i)
#pragma unroll
    for (int j = 0; j < 2; ++j) mfma_bf16(acc[i][j], av[i], bv[j]);
  __builtin_amdgcn_s_setprio(0);
}

__global__ __launch_bounds__(512, 2) void gemm_fc0(
    const unsigned short* __restrict__ A, const float* __restrict__ B,
    float* __restrict__ Cp, int M, int N, int K, int kz) {
  __shared__ unsigned short sA[2][FBM * FBK];  // 2 x 32 KB
  __shared__ float          sB[2][FBN * FBK];  // 2 x 32 KB  (fp32!)
  int tid = threadIdx.x;
  int lane = tid & 63, wave = tid >> 6;
  int bid = blockIdx.x;
  int z = bid & 7;                  // low bits -> XCD affinity per z-slice
  int mn = bid >> 3;
  int m0 = (mn & 3) * FBM;
  int n0 = (mn >> 2) * FBN;
  int wm = wave >> 2, wn = wave & 3;
  int wr = wm * 128, wc = wn * 32;
  int l15 = lane & 15, l4 = lane >> 4;
  int kbase = z * kz;
  int nt = kz / FBK;                // 124

  f32x4 acc[8][2];
#pragma unroll
  for (int i = 0; i < 8; ++i)
#pragma unroll
    for (int j = 0; j < 2; ++j) acc[i][j] = (f32x4){0.f, 0.f, 0.f, 0.f};

  // per-thread staging descriptors (loop-invariant part of addresses)
  size_t aOff[4]; int aDst[4];
  size_t bOff[4]; int bDst[4];
#pragma unroll
  for (int it = 0; it < 4; ++it) {
    int c = it * 512 + tid;
    {
      int r = c >> 3, p = c & 7;
      aOff[it] = (size_t)(m0 + r) * K + ((p ^ (r & 7)) << 3);
      aDst[it] = c * 8;
    }
    {
      int r = c >> 4, s = c & 15;
      bOff[it] = (size_t)(n0 + r) * K + ((s ^ ((r & 7) << 1)) << 2);
      bDst[it] = c * 4;
    }
  }

#define FC0_STAGE_HALF(buf, kt, h)                                             \
  _Pragma("unroll") for (int it = (h) * 2; it < (h) * 2 + 2; ++it) {           \
    __builtin_amdgcn_global_load_lds(                                          \
        (const __attribute__((address_space(1))) void*)(A + aOff[it] + (kt)),  \
        (__attribute__((address_space(3))) void*)(&sA[buf][aDst[it]]), 16, 0, 0); \
    __builtin_amdgcn_global_load_lds(                                          \
        (const __attribute__((address_space(1))) void*)(B + bOff[it] + (kt)),  \
        (__attribute__((address_space(3))) void*)(&sB[buf][bDst[it]]), 16, 0, 0); \
  }

  // prologue: stage tile 0 fully (8 loads/thread in flight)
  FC0_STAGE_HALF(0, kbase, 0)
  FC0_STAGE_HALF(0, kbase, 1)

  for (int t = 0; t < nt; ++t) {
    int cur = t & 1, nxt = cur ^ 1;
    int ktn = kbase + (t + 1) * FBK;
    bool pf = (t + 1 < nt);
    // ---- phase 0 (kk=0): prefetch half0 of next, counted wait for cur ----
    if (pf) {
      FC0_STAGE_HALF(nxt, ktn, 0)
      asm volatile("s_waitcnt vmcnt(4)" ::: "memory");  // cur's 8 done
    } else {
      asm volatile("s_waitcnt vmcnt(0)" ::: "memory");  // last tile: drain
    }
    __builtin_amdgcn_sched_barrier(0);
    __builtin_amdgcn_s_barrier();
    __builtin_amdgcn_sched_barrier(0);
    fc0_phase(sA[cur], sB[cur], 0, wr, wc, l15, l4, acc);
    __builtin_amdgcn_sched_barrier(0);
    __builtin_amdgcn_s_barrier();
    __builtin_amdgcn_sched_barrier(0);
    // ---- phase 1 (kk=1): prefetch half1 of next, no wait needed ----
    if (pf) { FC0_STAGE_HALF(nxt, ktn, 1) }
    fc0_phase(sA[cur], sB[cur], 1, wr, wc, l15, l4, acc);
    __builtin_amdgcn_sched_barrier(0);
    __builtin_amdgcn_s_barrier();
    __builtin_amdgcn_sched_barrier(0);
  }
#undef FC0_STAGE_HALF

  asm volatile("s_nop 7\n\ts_nop 7\n\ts_nop 7" ::: "memory");
  float* cp = Cp + (size_t)z * M * N;
#pragma unroll
  for (int i = 0; i < 8; ++i) {
    int rbase = m0 + wr + i * 16 + l4 * 4;
#pragma unroll
    for (int j = 0; j < 2; ++j) {
      int cc = n0 + wc + j * 16 + l15;
#pragma unroll
      for (int r = 0; r < 4; ++r)
        cp[(size_t)(rbase + r) * N + cc] = acc[i][j][r];
    }
  }
}

// ---- legacy GEMM (kept for fc1): 256x128 block tile, 4 waves, 2-barrier ----
#define BM 256
#define BN 128
#define BK 64

__global__ __launch_bounds__(256, 2) void gemm_bt(
    const unsigned short* __restrict__ A, const float* __restrict__ B,
    float* __restrict__ Cp, int M, int N, int K, int kz) {
  __shared__ unsigned short sA[BM * BK];   // 32 KB
  __shared__ unsigned short sB[BN * BK];   // 16 KB
  int tid = threadIdx.x;
  int lane = tid & 63, wave = tid >> 6;
  int n0 = blockIdx.x * BN, m0 = blockIdx.y * BM;
  int z = blockIdx.z;
  int wr = (wave >> 1) * 128, wc = (wave & 1) * 64;
  int l15 = lane & 15, l4 = lane >> 4;
  f32x4 acc[8][4];
#pragma unroll
  for (int i = 0; i < 8; ++i)
#pragma unroll
    for (int j = 0; j < 4; ++j) acc[i][j] = (f32x4){0.f, 0.f, 0.f, 0.f};

  int kend = z * kz + kz;
  for (int kt = z * kz; kt < kend; kt += BK) {
#pragma unroll
    for (int it = 0; it < 8; ++it) {
      int c = it * 256 + tid;
      int r = c >> 3, p = c & 7;
      int gcol = (p ^ (r & 7)) * 8;
      const unsigned short* gp = A + (size_t)(m0 + r) * K + kt + gcol;
      __builtin_amdgcn_global_load_lds(
          (const __attribute__((address_space(1))) void*)gp,
          (__attribute__((address_space(3))) void*)(&sA[c * 8]), 16, 0, 0);
    }
#pragma unroll
    for (int it = 0; it < 4; ++it) {
      int c = it * 256 + tid;
      int r = c >> 3, l = c & 7;
      const float* gp = B + (size_t)(n0 + r) * K + kt + l * 8;
      float4 f0 = *(const float4*)gp;
      float4 f1 = *(const float4*)(gp + 4);
      uint4v q;
      q.x = pk_bf16(f0.x, f0.y); q.y = pk_bf16(f0.z, f0.w);
      q.z = pk_bf16(f1.x, f1.y); q.w = pk_bf16(f1.z, f1.w);
      int p = l ^ (r & 7);
      *(uint4v*)(&sB[(r * 8 + p) * 8]) = q;
    }
    __syncthreads();
#pragma unroll
    for (int kk = 0; kk < 2; ++kk) {
      int lc = kk * 4 + l4;
      int4v av[8], bv[4];
#pragma unroll
      for (int i = 0; i < 8; ++i) {
        int ar = wr + i * 16 + l15;
        av[i] = *(const int4v*)&sA[(ar * 8 + (lc ^ (ar & 7))) * 8];
      }
#pragma unroll
      for (int j = 0; j < 4; ++j) {
        int br = wc + j * 16 + l15;
        bv[j] = *(const int4v*)&sB[(br * 8 + (lc ^ (br & 7))) * 8];
      }
#pragma unroll
      for (int i = 0; i < 8; ++i)
#pragma unroll
        for (int j = 0; j < 4; ++j) mfma_bf16(acc[i][j], av[i], bv[j]);
    }
    __syncthreads();
  }
  asm volatile("s_nop 7\n\ts_nop 7\n\ts_nop 7" ::: "memory");
  float* cp = Cp + (size_t)z * M * N;
#pragma unroll
  for (int i = 0; i < 8; ++i) {
    int rbase = m0 + wr + i * 16 + l4 * 4;
#pragma unroll
    for (int j = 0; j < 4; ++j) {
      int cc = n0 + wc + j * 16 + l15;
#pragma unroll
      for (int r = 0; r < 4; ++r)
        cp[(size_t)(rbase + r) * N + cc] = acc[i][j][r];
    }
  }
}

// --------------------- splitK reduce + bias + relu -------------------------
__global__ __launch_bounds__(256) void reduce_bias_act(
    const float* __restrict__ parts, const float* __restrict__ bias,
    int MN, int nmask, int nz, unsigned short* __restrict__ out_bf,
    float* __restrict__ out_f) {
  int idx = blockIdx.x * 256 + threadIdx.x;
  if (idx >= MN) return;
  float s = 0.f;
  for (int z = 0; z < nz; ++z) s += parts[(size_t)z * MN + idx];
  s += bias[idx & nmask];
  s = fmaxf(s, 0.f);
  if (out_bf) out_bf[idx] = f32_bf16(s);
  else out_f[idx] = s;
}

// ------------------------------ fc2 + sigmoid ------------------------------
__global__ __launch_bounds__(256) void fc2_kernel(
    const float* __restrict__ h2, const float* __restrict__ w,
    const float* __restrict__ b, float* __restrict__ out) {
  int wave = threadIdx.x >> 6, lane = threadIdx.x & 63;
  int row = blockIdx.x * 4 + wave;
  const float4* hp = (const float4*)(h2 + (size_t)row * 512);
  const float4* wp = (const float4*)w;
  int i0 = lane * 2;
  float4 a0 = hp[i0], a1 = hp[i0 + 1];
  float4 w0 = wp[i0], w1 = wp[i0 + 1];
  float s = a0.x * w0.x + a0.y * w0.y + a0.z * w0.z + a0.w * w0.w +
            a1.x * w1.x + a1.y * w1.y + a1.z * w1.z + a1.w * w1.w;
#pragma unroll
  for (int off = 32; off > 0; off >>= 1) s += __shfl_down(s, off);
  if (lane == 0) out[row] = 1.f / (1.f + expf(-(s + b[0])));
}

// ---------------------------------------------------------------------------
extern "C" void kernel_launch(void* const* d_in, const int* in_sizes, int n_in,
                              void* d_out, int out_size, void* d_ws, size_t ws_size,
                              hipStream_t stream) {
  const float* x     = (const float*)d_in[0];
  const float* Wb1   = (const float*)d_in[1];
  const float* Wb2   = (const float*)d_in[2];
  const float* se_w1 = (const float*)d_in[3];
  const float* se_w2 = (const float*)d_in[4];
  const float* fc0_w = (const float*)d_in[5];
  const float* fc0_b = (const float*)d_in[6];
  const float* fc1_w = (const float*)d_in[7];
  const float* fc1_b = (const float*)d_in[8];
  const float* fc2_w = (const float*)d_in[9];
  const float* fc2_b = (const float*)d_in[10];
  (void)in_sizes; (void)n_in; (void)out_size; (void)ws_size;

  char* ws = (char*)d_ws;
  float*          scale = (float*)(ws + 0);                   //  128 KB
  float*          t1    = (float*)(ws + 131072);              //  7.75 MB
  float*          t2    = (float*)(ws + 8257536);             //  7.75 MB
  unsigned short* feat  = (unsigned short*)(ws + 16384000);   //  124 MB bf16
  float*          hp    = (float*)(ws + 146407424);           //  64 MB partials
  unsigned short* h1b   = (unsigned short*)(ws + 213516288);  //  2 MB bf16
  float*          h2    = (float*)(ws + 215613440);           //  2 MB
  float*          out   = (float*)d_out;

  se_kernel<<<1024, 256, 0, stream>>>(x, se_w1, se_w2, scale);
  t_kernel<<<dim3(31, 16, 2), 256, 0, stream>>>(x, Wb1, Wb2, scale, t1, t2);
  feat_kernel<<<31744, 256, 0, stream>>>(x, t1, t2, scale, feat);
  // fc0: M=1024 N=1024 K=63488, splitK=8 (kz=7936 = 124 k-tiles), 256 blocks
  gemm_fc0<<<256, 512, 0, stream>>>(feat, fc0_w, hp, 1024, 1024, 63488, 7936);
  reduce_bias_act<<<4096, 256, 0, stream>>>(hp, fc0_b, 1024 * 1024, 1023, 8, h1b, nullptr);
  // fc1: M=1024 N=512 K=1024, splitK=16 (kz=64)
  gemm_bt<<<dim3(4, 4, 16), 256, 0, stream>>>(h1b, fc1_w, hp, 1024, 512, 1024, 64);
  reduce_bias_act<<<2048, 256, 0, stream>>>(hp, fc1_b, 1024 * 512, 511, 16, nullptr, h2);
  fc2_kernel<<<256, 256, 0, stream>>>(h2, fc2_w, fc2_b, out);
}

// Round 2
// 555.228 us; speedup vs baseline: 1.2631x; 1.2631x over previous
//
#include <hip/hip_runtime.h>
#include <hip/hip_bf16.h>
#include <stdint.h>

// ---------------------------------------------------------------------------
// FiBiNet forward, MI355X (gfx950).  R4: fc0 GEMM = 256x256x64 dbuf pipeline,
// 8 waves (2Mx4N, wave tile 128x64), A via pre-swizzled global_load_lds,
// B reg-staged fp32->cvt_pk->bf16 swizzled ds_write (R2-proven conflict-free
// 128B-row layout), ONE barrier/tile, counted vmcnt (never 0 mid-loop).
// R3 post-mortem: fp32-B LDS (256B rows) was ~8-way bank-conflicted and the
// 128x32 wave tile halved MFMA:LDS intensity -> LDS-bound at 353us.
// ---------------------------------------------------------------------------

typedef __attribute__((ext_vector_type(4))) int   int4v;
typedef __attribute__((ext_vector_type(4))) unsigned uint4v;
typedef __attribute__((ext_vector_type(4))) float f32x4;

__device__ __forceinline__ unsigned short f32_bf16(float f) {
  unsigned u = __builtin_bit_cast(unsigned, f);
  u = (u + 0x7fffu + ((u >> 16) & 1u)) >> 16;   // RNE
  return (unsigned short)u;
}
__device__ __forceinline__ unsigned pk_bf16(float lo, float hi) {
  return (unsigned)f32_bf16(lo) | ((unsigned)f32_bf16(hi) << 16);
}
__device__ __forceinline__ unsigned cvt_pk(float lo, float hi) {
  unsigned r;
  asm("v_cvt_pk_bf16_f32 %0, %1, %2" : "=v"(r) : "v"(lo), "v"(hi));
  return r;
}

// ------------------------------- SE block ----------------------------------
__global__ __launch_bounds__(256) void se_kernel(
    const float* __restrict__ x, const float* __restrict__ w1,
    const float* __restrict__ w2, float* __restrict__ scale) {
  __shared__ float Z[32];
  __shared__ float A1[4];
  int b = blockIdx.x;
  int t = threadIdx.x;
  int f = t >> 3, sub = t & 7;
  const float4* xp = (const float4*)(x + (size_t)b * 2048 + f * 64 + sub * 8);
  float4 v0 = xp[0], v1 = xp[1];
  float s = v0.x + v0.y + v0.z + v0.w + v1.x + v1.y + v1.z + v1.w;
  s += __shfl_down(s, 4, 8);
  s += __shfl_down(s, 2, 8);
  s += __shfl_down(s, 1, 8);
  if (sub == 0) Z[f] = s * (1.0f / 64.0f);
  __syncthreads();
  if (t < 4) {
    float a = 0.f;
#pragma unroll
    for (int ff = 0; ff < 32; ++ff) a += Z[ff] * w1[t * 32 + ff];
    A1[t] = fmaxf(a, 0.f);
  }
  __syncthreads();
  if (t < 32) {
    float a = 0.f;
#pragma unroll
    for (int r = 0; r < 4; ++r) a += A1[r] * w2[t * 4 + r];
    scale[b * 32 + t] = 1.f / (1.f + expf(-a));
  }
}

// -------------------- per-field bilinear transforms ------------------------
__global__ __launch_bounds__(256) void t_kernel(
    const float* __restrict__ x, const float* __restrict__ W1,
    const float* __restrict__ W2, const float* __restrict__ scale,
    float* __restrict__ t1, float* __restrict__ t2) {
  __shared__ float Wl[64 * 65];
  __shared__ float xs[64 * 65];
  int f = blockIdx.x;
  int b0 = blockIdx.y * 64;
  int which = blockIdx.z;
  const float* W = (which ? W2 : W1) + (size_t)f * 4096;
  float* tout = which ? t2 : t1;
  int t = threadIdx.x;
#pragma unroll
  for (int it = 0; it < 16; ++it) {
    int idx = it * 256 + t;
    int o = idx >> 6, e = idx & 63;
    Wl[o * 65 + e] = W[idx];
  }
#pragma unroll
  for (int it = 0; it < 16; ++it) {
    int idx = it * 256 + t;
    int bl = idx >> 6, e = idx & 63;
    float v = x[(size_t)(b0 + bl) * 2048 + f * 64 + e];
    if (which) v *= scale[(b0 + bl) * 32 + f];
    xs[bl * 65 + e] = v;
  }
  __syncthreads();
  int o = t & 63, g = t >> 6;
  float sum[16];
#pragma unroll
  for (int r = 0; r < 16; ++r) sum[r] = 0.f;
#pragma unroll 4
  for (int e = 0; e < 64; ++e) {
    float wv = Wl[o * 65 + e];
#pragma unroll
    for (int r = 0; r < 16; ++r) sum[r] += xs[(g * 16 + r) * 65 + e] * wv;
  }
#pragma unroll
  for (int r = 0; r < 16; ++r)
    tout[(size_t)(b0 + g * 16 + r) * 1984 + f * 64 + o] = sum[r];
}

// ----------------------- pair feature materialization ----------------------
__global__ __launch_bounds__(256) void feat_kernel(
    const float* __restrict__ x, const float* __restrict__ t1,
    const float* __restrict__ t2, const float* __restrict__ scale,
    unsigned short* __restrict__ feat) {
  int gid = blockIdx.x * 256 + threadIdx.x;
  int b = gid / 7936;
  int rem = gid - b * 7936;
  int s = rem >> 3;
  int e0 = (rem & 7) * 8;
  int which = (s >= 496) ? 1 : 0;
  int p = s - (which ? 496 : 0);
  int i = (int)((63.0f - sqrtf((float)(3969 - 8 * p))) * 0.5f);
  while ((i * (63 - i)) / 2 > p) --i;
  while (((i + 1) * (62 - i)) / 2 <= p) ++i;
  int j = i + 1 + (p - (i * (63 - i)) / 2);
  const float* tp = (which ? t2 : t1) + (size_t)b * 1984 + i * 64 + e0;
  const float* xp = x + (size_t)b * 2048 + j * 64 + e0;
  float sc = which ? scale[b * 32 + j] : 1.0f;
  float4 ta = *(const float4*)tp, tb = *(const float4*)(tp + 4);
  float4 xa = *(const float4*)xp, xb = *(const float4*)(xp + 4);
  uint4v o;
  o.x = pk_bf16(ta.x * xa.x * sc, ta.y * xa.y * sc);
  o.y = pk_bf16(ta.z * xa.z * sc, ta.w * xa.w * sc);
  o.z = pk_bf16(tb.x * xb.x * sc, tb.y * xb.y * sc);
  o.w = pk_bf16(tb.z * xb.z * sc, tb.w * xb.w * sc);
  *(uint4v*)(feat + (size_t)b * 63488 + s * 64 + e0) = o;
}

// ------------------------------- MFMA GEMM ---------------------------------
__device__ __forceinline__ void mfma_bf16(f32x4& d, int4v a, int4v b) {
  asm volatile("v_mfma_f32_16x16x32_bf16 %0, %1, %2, %0"
               : "+v"(d) : "v"(a), "v"(b));
}

// ---- fc0 pipeline GEMM: 256x256 tile, BK=64, 512 thr (8 waves 2Mx4N).
#define FBM 256
#define FBN 256
#define FBK 64

__device__ __forceinline__ void fc0_phase(
    const unsigned short* sAb, const unsigned short* sBb,
    int kk, int wr, int wc, int l15, int l4, f32x4 (&acc)[8][4]) {
  int4v av[8], bv[4];
#pragma unroll
  for (int i = 0; i < 8; ++i) {
    int ar = wr + i * 16 + l15;
    av[i] = *(const int4v*)&sAb[(ar * 8 + ((kk * 4 + l4) ^ (ar & 7))) * 8];
  }
#pragma unroll
  for (int j = 0; j < 4; ++j) {
    int br = wc + j * 16 + l15;
    bv[j] = *(const int4v*)&sBb[(br * 8 + ((kk * 4 + l4) ^ (br & 7))) * 8];
  }
  __builtin_amdgcn_s_setprio(1);
#pragma unroll
  for (int i = 0; i < 8; ++i)
#pragma unroll
    for (int j = 0; j < 4; ++j) mfma_bf16(acc[i][j], av[i], bv[j]);
  __builtin_amdgcn_s_setprio(0);
}

__global__ __launch_bounds__(512, 2) void gemm_fc0(
    const unsigned short* __restrict__ A, const float* __restrict__ Bp,
    float* __restrict__ Cp, int M, int N, int K, int kz) {
  __shared__ unsigned short sA[2][FBM * FBK];  // 2 x 32 KB bf16
  __shared__ unsigned short sB[2][FBN * FBK];  // 2 x 32 KB bf16
  int tid = threadIdx.x;
  int lane = tid & 63;
  int wave = tid >> 6;
  // bid = s + 64*m, s = n + 4*z : the 4 m-blocks of one (n,z) share an XCD
  int bid = blockIdx.x;
  int m0 = (bid >> 6) << 8;
  int s  = bid & 63;
  int n0 = (s & 3) << 8;
  int z  = s >> 2;                 // 0..15
  int wr = (wave >> 2) * 128, wc = (wave & 3) * 64;
  int l15 = lane & 15, l4 = lane >> 4;
  int kbase = z * kz;
  int nt = kz / FBK;               // 62

  f32x4 acc[8][4];
#pragma unroll
  for (int i = 0; i < 8; ++i)
#pragma unroll
    for (int j = 0; j < 4; ++j) acc[i][j] = (f32x4){0.f, 0.f, 0.f, 0.f};

  // staging maps: 2048 chunks of 16B out per operand; 4 chunks/thread
  unsigned aOff[4]; int aDst[4];
  unsigned bOff[4]; int bDst[4];
#pragma unroll
  for (int it = 0; it < 4; ++it) {
    int c = it * 512 + tid;
    int r = c >> 3, l = c & 7;
    aOff[it] = (unsigned)(m0 + r) * (unsigned)K + (unsigned)((l ^ (r & 7)) << 3);
    aDst[it] = c * 8;                       // shorts (16B chunks, linear)
    bOff[it] = (unsigned)(n0 + r) * (unsigned)K + (unsigned)(l << 3);
    bDst[it] = (r * 8 + (l ^ (r & 7))) * 8; // shorts (swizzled dest)
  }

#define FC0_STAGE_A(buf, kt)                                                   \
  _Pragma("unroll") for (int it = 0; it < 4; ++it) {                           \
    __builtin_amdgcn_global_load_lds(                                          \
        (const __attribute__((address_space(1))) void*)(A + aOff[it] + (kt)),  \
        (__attribute__((address_space(3))) void*)(&sA[buf][aDst[it]]), 16, 0, 0); \
  }
#define FC0_LOAD_B(kt)                                                         \
  _Pragma("unroll") for (int it = 0; it < 4; ++it) {                           \
    const float* gp = Bp + bOff[it] + (kt);                                    \
    bst[2 * it]     = *(const float4*)gp;                                      \
    bst[2 * it + 1] = *(const float4*)(gp + 4);                                \
  }
#define FC0_WRITE_B(buf)                                                       \
  _Pragma("unroll") for (int it = 0; it < 4; ++it) {                           \
    uint4v q;                                                                  \
    q.x = cvt_pk(bst[2 * it].x, bst[2 * it].y);                                \
    q.y = cvt_pk(bst[2 * it].z, bst[2 * it].w);                                \
    q.z = cvt_pk(bst[2 * it + 1].x, bst[2 * it + 1].y);                        \
    q.w = cvt_pk(bst[2 * it + 1].z, bst[2 * it + 1].w);                        \
    *(uint4v*)(&sB[buf][bDst[it]]) = q;                                        \
  }

  float4 bst[8];
  // ---- prologue: B0 -> regs -> sB[0]; A0 DMA -> sA[0]; B1 -> regs ----
  FC0_LOAD_B(kbase)
  FC0_WRITE_B(0)                          // compiler inserts vmcnt for bst
  FC0_STAGE_A(0, kbase)                   // 4 outstanding (A0)
  FC0_LOAD_B(kbase + FBK)                 // +8 (B1) = 12
  __builtin_amdgcn_sched_barrier(0);
  asm volatile("s_waitcnt vmcnt(8) lgkmcnt(0)" ::: "memory");  // A0 done, B1 in flight
  __builtin_amdgcn_sched_barrier(0);
  __builtin_amdgcn_s_barrier();
  __builtin_amdgcn_sched_barrier(0);

  for (int t = 0; t < nt; ++t) {
    int cur = t & 1, nxt = cur ^ 1;
    // step 1: A(t+1) DMA into sA[nxt] (last read of sA[nxt] was t-1, barrier'd)
    if (t + 1 < nt) { FC0_STAGE_A(nxt, kbase + (t + 1) * FBK) }
    __builtin_amdgcn_sched_barrier(0);
    // step 2: compute kk=0 on cur
    fc0_phase(sA[cur], sB[cur], 0, wr, wc, l15, l4, acc);
    __builtin_amdgcn_sched_barrier(0);
    // step 3: drain B(t+1) regs (8 oldest of 12), convert, publish sB[nxt]
    if (t + 1 < nt) {
      asm volatile("s_waitcnt vmcnt(4)" ::: "memory");
      __builtin_amdgcn_sched_barrier(0);
      FC0_WRITE_B(nxt)
    }
    __builtin_amdgcn_sched_barrier(0);
    // step 4: issue B(t+2) global loads into freed regs
    if (t + 2 < nt) { FC0_LOAD_B(kbase + (t + 2) * FBK) }
    __builtin_amdgcn_sched_barrier(0);
    // step 5: compute kk=1 on cur
    fc0_phase(sA[cur], sB[cur], 1, wr, wc, l15, l4, acc);
    __builtin_amdgcn_sched_barrier(0);
    // step 6: A(t+1) DMA done (leave B(t+2) in flight), ds_writes done, barrier
    if (t + 2 < nt) {
      asm volatile("s_waitcnt vmcnt(8) lgkmcnt(0)" ::: "memory");
    } else {
      asm volatile("s_waitcnt vmcnt(0) lgkmcnt(0)" ::: "memory");
    }
    __builtin_amdgcn_sched_barrier(0);
    __builtin_amdgcn_s_barrier();
    __builtin_amdgcn_sched_barrier(0);
  }
#undef FC0_STAGE_A
#undef FC0_LOAD_B
#undef FC0_WRITE_B

  asm volatile("s_nop 7\n\ts_nop 7\n\ts_nop 7" ::: "memory");
  float* cp = Cp + (size_t)z * M * N;
#pragma unroll
  for (int i = 0; i < 8; ++i) {
    int rbase = m0 + wr + i * 16 + l4 * 4;
#pragma unroll
    for (int j = 0; j < 4; ++j) {
      int cc = n0 + wc + j * 16 + l15;
#pragma unroll
      for (int r = 0; r < 4; ++r)
        cp[(size_t)(rbase + r) * N + cc] = acc[i][j][r];
    }
  }
}

// ---- legacy GEMM (kept for fc1): 256x128 block tile, 4 waves, 2-barrier ----
#define BM 256
#define BN 128
#define BK 64

__global__ __launch_bounds__(256, 2) void gemm_bt(
    const unsigned short* __restrict__ A, const float* __restrict__ B,
    float* __restrict__ Cp, int M, int N, int K, int kz) {
  __shared__ unsigned short sA[BM * BK];   // 32 KB
  __shared__ unsigned short sB[BN * BK];   // 16 KB
  int tid = threadIdx.x;
  int lane = tid & 63, wave = tid >> 6;
  int n0 = blockIdx.x * BN, m0 = blockIdx.y * BM;
  int z = blockIdx.z;
  int wr = (wave >> 1) * 128, wc = (wave & 1) * 64;
  int l15 = lane & 15, l4 = lane >> 4;
  f32x4 acc[8][4];
#pragma unroll
  for (int i = 0; i < 8; ++i)
#pragma unroll
    for (int j = 0; j < 4; ++j) acc[i][j] = (f32x4){0.f, 0.f, 0.f, 0.f};

  int kend = z * kz + kz;
  for (int kt = z * kz; kt < kend; kt += BK) {
#pragma unroll
    for (int it = 0; it < 8; ++it) {
      int c = it * 256 + tid;
      int r = c >> 3, p = c & 7;
      int gcol = (p ^ (r & 7)) * 8;
      const unsigned short* gp = A + (size_t)(m0 + r) * K + kt + gcol;
      __builtin_amdgcn_global_load_lds(
          (const __attribute__((address_space(1))) void*)gp,
          (__attribute__((address_space(3))) void*)(&sA[c * 8]), 16, 0, 0);
    }
#pragma unroll
    for (int it = 0; it < 4; ++it) {
      int c = it * 256 + tid;
      int r = c >> 3, l = c & 7;
      const float* gp = B + (size_t)(n0 + r) * K + kt + l * 8;
      float4 f0 = *(const float4*)gp;
      float4 f1 = *(const float4*)(gp + 4);
      uint4v q;
      q.x = pk_bf16(f0.x, f0.y); q.y = pk_bf16(f0.z, f0.w);
      q.z = pk_bf16(f1.x, f1.y); q.w = pk_bf16(f1.z, f1.w);
      int p = l ^ (r & 7);
      *(uint4v*)(&sB[(r * 8 + p) * 8]) = q;
    }
    __syncthreads();
#pragma unroll
    for (int kk = 0; kk < 2; ++kk) {
      int lc = kk * 4 + l4;
      int4v av[8], bv[4];
#pragma unroll
      for (int i = 0; i < 8; ++i) {
        int ar = wr + i * 16 + l15;
        av[i] = *(const int4v*)&sA[(ar * 8 + (lc ^ (ar & 7))) * 8];
      }
#pragma unroll
      for (int j = 0; j < 4; ++j) {
        int br = wc + j * 16 + l15;
        bv[j] = *(const int4v*)&sB[(br * 8 + (lc ^ (br & 7))) * 8];
      }
#pragma unroll
      for (int i = 0; i < 8; ++i)
#pragma unroll
        for (int j = 0; j < 4; ++j) mfma_bf16(acc[i][j], av[i], bv[j]);
    }
    __syncthreads();
  }
  asm volatile("s_nop 7\n\ts_nop 7\n\ts_nop 7" ::: "memory");
  float* cp = Cp + (size_t)z * M * N;
#pragma unroll
  for (int i = 0; i < 8; ++i) {
    int rbase = m0 + wr + i * 16 + l4 * 4;
#pragma unroll
    for (int j = 0; j < 4; ++j) {
      int cc = n0 + wc + j * 16 + l15;
#pragma unroll
      for (int r = 0; r < 4; ++r)
        cp[(size_t)(rbase + r) * N + cc] = acc[i][j][r];
    }
  }
}

// --------------------- splitK reduce + bias + relu -------------------------
__global__ __launch_bounds__(256) void reduce_bias_act(
    const float* __restrict__ parts, const float* __restrict__ bias,
    int MN, int nmask, int nz, unsigned short* __restrict__ out_bf,
    float* __restrict__ out_f) {
  int idx = blockIdx.x * 256 + threadIdx.x;
  if (idx >= MN) return;
  float s = 0.f;
  for (int z = 0; z < nz; ++z) s += parts[(size_t)z * MN + idx];
  s += bias[idx & nmask];
  s = fmaxf(s, 0.f);
  if (out_bf) out_bf[idx] = f32_bf16(s);
  else out_f[idx] = s;
}

// ------------------------------ fc2 + sigmoid ------------------------------
__global__ __launch_bounds__(256) void fc2_kernel(
    const float* __restrict__ h2, const float* __restrict__ w,
    const float* __restrict__ b, float* __restrict__ out) {
  int wave = threadIdx.x >> 6, lane = threadIdx.x & 63;
  int row = blockIdx.x * 4 + wave;
  const float4* hp = (const float4*)(h2 + (size_t)row * 512);
  const float4* wp = (const float4*)w;
  int i0 = lane * 2;
  float4 a0 = hp[i0], a1 = hp[i0 + 1];
  float4 w0 = wp[i0], w1 = wp[i0 + 1];
  float s = a0.x * w0.x + a0.y * w0.y + a0.z * w0.z + a0.w * w0.w +
            a1.x * w1.x + a1.y * w1.y + a1.z * w1.z + a1.w * w1.w;
#pragma unroll
  for (int off = 32; off > 0; off >>= 1) s += __shfl_down(s, off);
  if (lane == 0) out[row] = 1.f / (1.f + expf(-(s + b[0])));
}

// ---------------------------------------------------------------------------
extern "C" void kernel_launch(void* const* d_in, const int* in_sizes, int n_in,
                              void* d_out, int out_size, void* d_ws, size_t ws_size,
                              hipStream_t stream) {
  const float* x     = (const float*)d_in[0];
  const float* Wb1   = (const float*)d_in[1];
  const float* Wb2   = (const float*)d_in[2];
  const float* se_w1 = (const float*)d_in[3];
  const float* se_w2 = (const float*)d_in[4];
  const float* fc0_w = (const float*)d_in[5];
  const float* fc0_b = (const float*)d_in[6];
  const float* fc1_w = (const float*)d_in[7];
  const float* fc1_b = (const float*)d_in[8];
  const float* fc2_w = (const float*)d_in[9];
  const float* fc2_b = (const float*)d_in[10];
  (void)in_sizes; (void)n_in; (void)out_size; (void)ws_size;

  char* ws = (char*)d_ws;
  float*          scale = (float*)(ws + 0);                   //  128 KB
  float*          t1    = (float*)(ws + 131072);              //  7.75 MB
  float*          t2    = (float*)(ws + 8257536);             //  7.75 MB
  unsigned short* feat  = (unsigned short*)(ws + 16384000);   //  124 MB bf16
  float*          hp    = (float*)(ws + 146407424);           //  64 MB partials
  unsigned short* h1b   = (unsigned short*)(ws + 213516288);  //  2 MB bf16
  float*          h2    = (float*)(ws + 215613440);           //  2 MB
  float*          out   = (float*)d_out;

  se_kernel<<<1024, 256, 0, stream>>>(x, se_w1, se_w2, scale);
  t_kernel<<<dim3(31, 16, 2), 256, 0, stream>>>(x, Wb1, Wb2, scale, t1, t2);
  feat_kernel<<<31744, 256, 0, stream>>>(x, t1, t2, scale, feat);
  // fc0: M=1024 N=1024 K=63488, splitK=16 (kz=3968 = 62 k-tiles), 256 blocks
  gemm_fc0<<<256, 512, 0, stream>>>(feat, fc0_w, hp, 1024, 1024, 63488, 3968);
  reduce_bias_act<<<4096, 256, 0, stream>>>(hp, fc0_b, 1024 * 1024, 1023, 16, h1b, nullptr);
  // fc1: M=1024 N=512 K=1024, splitK=16 (kz=64)
  gemm_bt<<<dim3(4, 4, 16), 256, 0, stream>>>(h1b, fc1_w, hp, 1024, 512, 1024, 64);
  reduce_bias_act<<<2048, 256, 0, stream>>>(hp, fc1_b, 1024 * 512, 511, 16, nullptr, h2);
  fc2_kernel<<<256, 256, 0, stream>>>(h2, fc2_w, fc2_b, out);
}

// Round 3
// 537.055 us; speedup vs baseline: 1.3058x; 1.0338x over previous
//
#include <hip/hip_runtime.h>
#include <hip/hip_bf16.h>
#include <stdint.h>

// ---------------------------------------------------------------------------
// FiBiNet forward, MI355X (gfx950).  R5: fc0 pipeline DE-SERIALIZED.
// R4 post-mortem: sched_barrier(0) between every step reproduced m141's
// order-pinning regression (all pipes <30% busy, 7660 cyc/tile vs ~2500
// floor).  R5 keeps the R4 skeleton (256x256x64 dbuf, A gload_lds
// pre-swizzled, B reg-staged fp32->cvt_pk->swizzled ds_write, one barrier +
// counted vmcnt per tile) but frees the scheduler: only a VMEM-order fence
// (sched_barrier 0x38F) per tile to keep the vmcnt(8) count exact, unroll-2
// so buffer indices are compile-time (provable LDS disjointness), no setprio.
// ---------------------------------------------------------------------------

typedef __attribute__((ext_vector_type(4))) int   int4v;
typedef __attribute__((ext_vector_type(4))) unsigned uint4v;
typedef __attribute__((ext_vector_type(4))) float f32x4;

__device__ __forceinline__ unsigned short f32_bf16(float f) {
  unsigned u = __builtin_bit_cast(unsigned, f);
  u = (u + 0x7fffu + ((u >> 16) & 1u)) >> 16;   // RNE
  return (unsigned short)u;
}
__device__ __forceinline__ unsigned pk_bf16(float lo, float hi) {
  return (unsigned)f32_bf16(lo) | ((unsigned)f32_bf16(hi) << 16);
}
__device__ __forceinline__ unsigned cvt_pk(float lo, float hi) {
  unsigned r;
  asm("v_cvt_pk_bf16_f32 %0, %1, %2" : "=v"(r) : "v"(lo), "v"(hi));
  return r;
}

// ------------------------------- SE block ----------------------------------
__global__ __launch_bounds__(256) void se_kernel(
    const float* __restrict__ x, const float* __restrict__ w1,
    const float* __restrict__ w2, float* __restrict__ scale) {
  __shared__ float Z[32];
  __shared__ float A1[4];
  int b = blockIdx.x;
  int t = threadIdx.x;
  int f = t >> 3, sub = t & 7;
  const float4* xp = (const float4*)(x + (size_t)b * 2048 + f * 64 + sub * 8);
  float4 v0 = xp[0], v1 = xp[1];
  float s = v0.x + v0.y + v0.z + v0.w + v1.x + v1.y + v1.z + v1.w;
  s += __shfl_down(s, 4, 8);
  s += __shfl_down(s, 2, 8);
  s += __shfl_down(s, 1, 8);
  if (sub == 0) Z[f] = s * (1.0f / 64.0f);
  __syncthreads();
  if (t < 4) {
    float a = 0.f;
#pragma unroll
    for (int ff = 0; ff < 32; ++ff) a += Z[ff] * w1[t * 32 + ff];
    A1[t] = fmaxf(a, 0.f);
  }
  __syncthreads();
  if (t < 32) {
    float a = 0.f;
#pragma unroll
    for (int r = 0; r < 4; ++r) a += A1[r] * w2[t * 4 + r];
    scale[b * 32 + t] = 1.f / (1.f + expf(-a));
  }
}

// -------------------- per-field bilinear transforms ------------------------
__global__ __launch_bounds__(256) void t_kernel(
    const float* __restrict__ x, const float* __restrict__ W1,
    const float* __restrict__ W2, const float* __restrict__ scale,
    float* __restrict__ t1, float* __restrict__ t2) {
  __shared__ float Wl[64 * 65];
  __shared__ float xs[64 * 65];
  int f = blockIdx.x;
  int b0 = blockIdx.y * 64;
  int which = blockIdx.z;
  const float* W = (which ? W2 : W1) + (size_t)f * 4096;
  float* tout = which ? t2 : t1;
  int t = threadIdx.x;
#pragma unroll
  for (int it = 0; it < 16; ++it) {
    int idx = it * 256 + t;
    int o = idx >> 6, e = idx & 63;
    Wl[o * 65 + e] = W[idx];
  }
#pragma unroll
  for (int it = 0; it < 16; ++it) {
    int idx = it * 256 + t;
    int bl = idx >> 6, e = idx & 63;
    float v = x[(size_t)(b0 + bl) * 2048 + f * 64 + e];
    if (which) v *= scale[(b0 + bl) * 32 + f];
    xs[bl * 65 + e] = v;
  }
  __syncthreads();
  int o = t & 63, g = t >> 6;
  float sum[16];
#pragma unroll
  for (int r = 0; r < 16; ++r) sum[r] = 0.f;
#pragma unroll 4
  for (int e = 0; e < 64; ++e) {
    float wv = Wl[o * 65 + e];
#pragma unroll
    for (int r = 0; r < 16; ++r) sum[r] += xs[(g * 16 + r) * 65 + e] * wv;
  }
#pragma unroll
  for (int r = 0; r < 16; ++r)
    tout[(size_t)(b0 + g * 16 + r) * 1984 + f * 64 + o] = sum[r];
}

// ----------------------- pair feature materialization ----------------------
__global__ __launch_bounds__(256) void feat_kernel(
    const float* __restrict__ x, const float* __restrict__ t1,
    const float* __restrict__ t2, const float* __restrict__ scale,
    unsigned short* __restrict__ feat) {
  int gid = blockIdx.x * 256 + threadIdx.x;
  int b = gid / 7936;
  int rem = gid - b * 7936;
  int s = rem >> 3;
  int e0 = (rem & 7) * 8;
  int which = (s >= 496) ? 1 : 0;
  int p = s - (which ? 496 : 0);
  int i = (int)((63.0f - sqrtf((float)(3969 - 8 * p))) * 0.5f);
  while ((i * (63 - i)) / 2 > p) --i;
  while (((i + 1) * (62 - i)) / 2 <= p) ++i;
  int j = i + 1 + (p - (i * (63 - i)) / 2);
  const float* tp = (which ? t2 : t1) + (size_t)b * 1984 + i * 64 + e0;
  const float* xp = x + (size_t)b * 2048 + j * 64 + e0;
  float sc = which ? scale[b * 32 + j] : 1.0f;
  float4 ta = *(const float4*)tp, tb = *(const float4*)(tp + 4);
  float4 xa = *(const float4*)xp, xb = *(const float4*)(xp + 4);
  uint4v o;
  o.x = pk_bf16(ta.x * xa.x * sc, ta.y * xa.y * sc);
  o.y = pk_bf16(ta.z * xa.z * sc, ta.w * xa.w * sc);
  o.z = pk_bf16(tb.x * xb.x * sc, tb.y * xb.y * sc);
  o.w = pk_bf16(tb.z * xb.z * sc, tb.w * xb.w * sc);
  *(uint4v*)(feat + (size_t)b * 63488 + s * 64 + e0) = o;
}

// ------------------------------- MFMA GEMM ---------------------------------
__device__ __forceinline__ void mfma_bf16(f32x4& d, int4v a, int4v b) {
  asm volatile("v_mfma_f32_16x16x32_bf16 %0, %1, %2, %0"
               : "+v"(d) : "v"(a), "v"(b));
}

// ---- fc0 pipeline GEMM: 256x256 tile, BK=64, 512 thr (8 waves 2Mx4N).
#define FBM 256
#define FBN 256
#define FBK 64

__device__ __forceinline__ void fc0_phase(
    const unsigned short* sAb, const unsigned short* sBb,
    int kk, int wr, int wc, int l15, int l4, f32x4 (&acc)[8][4]) {
  int4v av[8], bv[4];
#pragma unroll
  for (int i = 0; i < 8; ++i) {
    int ar = wr + i * 16 + l15;
    av[i] = *(const int4v*)&sAb[(ar * 8 + ((kk * 4 + l4) ^ (ar & 7))) * 8];
  }
#pragma unroll
  for (int j = 0; j < 4; ++j) {
    int br = wc + j * 16 + l15;
    bv[j] = *(const int4v*)&sBb[(br * 8 + ((kk * 4 + l4) ^ (br & 7))) * 8];
  }
#pragma unroll
  for (int i = 0; i < 8; ++i)
#pragma unroll
    for (int j = 0; j < 4; ++j) mfma_bf16(acc[i][j], av[i], bv[j]);
}

__global__ __launch_bounds__(512, 2) void gemm_fc0(
    const unsigned short* __restrict__ A, const float* __restrict__ Bp,
    float* __restrict__ Cp, int M, int N, int K, int kz) {
  __shared__ unsigned short sA[2][FBM * FBK];  // 2 x 32 KB bf16
  __shared__ unsigned short sB[2][FBN * FBK];  // 2 x 32 KB bf16
  int tid = threadIdx.x;
  int lane = tid & 63;
  int wave = tid >> 6;
  // bid = s + 64*m, s = n + 4*z : the 4 m-blocks of one (n,z) share an XCD
  int bid = blockIdx.x;
  int m0 = (bid >> 6) << 8;
  int s  = bid & 63;
  int n0 = (s & 3) << 8;
  int z  = s >> 2;                 // 0..15
  int wr = (wave >> 2) * 128, wc = (wave & 3) * 64;
  int l15 = lane & 15, l4 = lane >> 4;
  int kbase = z * kz;
  int nt = kz / FBK;               // 62

  f32x4 acc[8][4];
#pragma unroll
  for (int i = 0; i < 8; ++i)
#pragma unroll
    for (int j = 0; j < 4; ++j) acc[i][j] = (f32x4){0.f, 0.f, 0.f, 0.f};

  // staging maps: 2048 chunks of 16B out per operand; 4 chunks/thread
  unsigned aOff[4]; int aDst[4];
  unsigned bOff[4]; int bDst[4];
#pragma unroll
  for (int it = 0; it < 4; ++it) {
    int c = it * 512 + tid;
    int r = c >> 3, l = c & 7;
    aOff[it] = (unsigned)(m0 + r) * (unsigned)K + (unsigned)((l ^ (r & 7)) << 3);
    aDst[it] = c * 8;                       // shorts (16B chunks, linear)
    bOff[it] = (unsigned)(n0 + r) * (unsigned)K + (unsigned)(l << 3);
    bDst[it] = (r * 8 + (l ^ (r & 7))) * 8; // shorts (swizzled dest)
  }

#define FC0_STAGE_A(buf, kt)                                                   \
  _Pragma("unroll") for (int it = 0; it < 4; ++it) {                           \
    __builtin_amdgcn_global_load_lds(                                          \
        (const __attribute__((address_space(1))) void*)(A + aOff[it] + (kt)),  \
        (__attribute__((address_space(3))) void*)(&sA[buf][aDst[it]]), 16, 0, 0); \
  }
#define FC0_LOAD_B(kt)                                                         \
  _Pragma("unroll") for (int it = 0; it < 4; ++it) {                           \
    const float* gp = Bp + bOff[it] + (kt);                                    \
    bst[2 * it]     = *(const float4*)gp;                                      \
    bst[2 * it + 1] = *(const float4*)(gp + 4);                                \
  }
#define FC0_WRITE_B(buf)                                                       \
  _Pragma("unroll") for (int it = 0; it < 4; ++it) {                           \
    uint4v q;                                                                  \
    q.x = cvt_pk(bst[2 * it].x, bst[2 * it].y);                                \
    q.y = cvt_pk(bst[2 * it].z, bst[2 * it].w);                                \
    q.z = cvt_pk(bst[2 * it + 1].x, bst[2 * it + 1].y);                        \
    q.w = cvt_pk(bst[2 * it + 1].z, bst[2 * it + 1].w);                        \
    *(uint4v*)(&sB[buf][bDst[it]]) = q;                                        \
  }
// VMEM-only scheduling fence: ALU|VALU|SALU|MFMA|DS|DS_READ|DS_WRITE may
// cross, VMEM may not -> pins global-load issue order for counted vmcnt.
#define FENCE_VMEM() __builtin_amdgcn_sched_barrier(0x38F)

  float4 bst[8];
  // ---- prologue: B0 -> regs -> sB[0]; A0 DMA -> sA[0]; B1 -> regs ----
  FC0_LOAD_B(kbase)                       // 8 outstanding (B0)
  FENCE_VMEM();
  FC0_WRITE_B(0)                          // compiler drains B0 for cvt uses
  FC0_STAGE_A(0, kbase)                   // 4 outstanding (A0)
  FENCE_VMEM();
  FC0_LOAD_B(kbase + FBK)                 // +8 (B1) = 12
  asm volatile("s_waitcnt vmcnt(8) lgkmcnt(0)" ::: "memory");  // A0 done
  __builtin_amdgcn_s_barrier();

  // main loop: branch-free body, unroll 2 so cur/nxt are compile-time
  int t = 0;
#pragma unroll 2
  for (; t < nt - 2; ++t) {
    int cur = t & 1, nxt = cur ^ 1;
    FC0_STAGE_A(nxt, kbase + (t + 1) * FBK)        // A(t+1): 4 -> 12 total
    fc0_phase(sA[cur], sB[cur], 0, wr, wc, l15, l4, acc);
    FENCE_VMEM();                                  // A(t+1) issues before B(t+2)
    FC0_WRITE_B(nxt)                               // drains B(t+1) (compiler)
    FC0_LOAD_B(kbase + (t + 2) * FBK)              // B(t+2): 8 -> 12 total
    fc0_phase(sA[cur], sB[cur], 1, wr, wc, l15, l4, acc);
    asm volatile("s_waitcnt vmcnt(8) lgkmcnt(0)" ::: "memory");  // A(t+1) done
    __builtin_amdgcn_s_barrier();
  }
  // t = nt-2: stage+publish the last tile, drain everything
  {
    int cur = t & 1, nxt = cur ^ 1;
    FC0_STAGE_A(nxt, kbase + (t + 1) * FBK)
    fc0_phase(sA[cur], sB[cur], 0, wr, wc, l15, l4, acc);
    FC0_WRITE_B(nxt)
    fc0_phase(sA[cur], sB[cur], 1, wr, wc, l15, l4, acc);
    asm volatile("s_waitcnt vmcnt(0) lgkmcnt(0)" ::: "memory");
    __builtin_amdgcn_s_barrier();
    ++t;
    cur = t & 1;
    fc0_phase(sA[cur], sB[cur], 0, wr, wc, l15, l4, acc);
    fc0_phase(sA[cur], sB[cur], 1, wr, wc, l15, l4, acc);
  }
#undef FC0_STAGE_A
#undef FC0_LOAD_B
#undef FC0_WRITE_B
#undef FENCE_VMEM

  asm volatile("s_nop 7\n\ts_nop 7\n\ts_nop 7" ::: "memory");
  float* cp = Cp + (size_t)z * M * N;
#pragma unroll
  for (int i = 0; i < 8; ++i) {
    int rbase = m0 + wr + i * 16 + l4 * 4;
#pragma unroll
    for (int j = 0; j < 4; ++j) {
      int cc = n0 + wc + j * 16 + l15;
#pragma unroll
      for (int r = 0; r < 4; ++r)
        cp[(size_t)(rbase + r) * N + cc] = acc[i][j][r];
    }
  }
}

// ---- legacy GEMM (kept for fc1): 256x128 block tile, 4 waves, 2-barrier ----
#define BM 256
#define BN 128
#define BK 64

__global__ __launch_bounds__(256, 2) void gemm_bt(
    const unsigned short* __restrict__ A, const float* __restrict__ B,
    float* __restrict__ Cp, int M, int N, int K, int kz) {
  __shared__ unsigned short sA[BM * BK];   // 32 KB
  __shared__ unsigned short sB[BN * BK];   // 16 KB
  int tid = threadIdx.x;
  int lane = tid & 63, wave = tid >> 6;
  int n0 = blockIdx.x * BN, m0 = blockIdx.y * BM;
  int z = blockIdx.z;
  int wr = (wave >> 1) * 128, wc = (wave & 1) * 64;
  int l15 = lane & 15, l4 = lane >> 4;
  f32x4 acc[8][4];
#pragma unroll
  for (int i = 0; i < 8; ++i)
#pragma unroll
    for (int j = 0; j < 4; ++j) acc[i][j] = (f32x4){0.f, 0.f, 0.f, 0.f};

  int kend = z * kz + kz;
  for (int kt = z * kz; kt < kend; kt += BK) {
#pragma unroll
    for (int it = 0; it < 8; ++it) {
      int c = it * 256 + tid;
      int r = c >> 3, p = c & 7;
      int gcol = (p ^ (r & 7)) * 8;
      const unsigned short* gp = A + (size_t)(m0 + r) * K + kt + gcol;
      __builtin_amdgcn_global_load_lds(
          (const __attribute__((address_space(1))) void*)gp,
          (__attribute__((address_space(3))) void*)(&sA[c * 8]), 16, 0, 0);
    }
#pragma unroll
    for (int it = 0; it < 4; ++it) {
      int c = it * 256 + tid;
      int r = c >> 3, l = c & 7;
      const float* gp = B + (size_t)(n0 + r) * K + kt + l * 8;
      float4 f0 = *(const float4*)gp;
      float4 f1 = *(const float4*)(gp + 4);
      uint4v q;
      q.x = pk_bf16(f0.x, f0.y); q.y = pk_bf16(f0.z, f0.w);
      q.z = pk_bf16(f1.x, f1.y); q.w = pk_bf16(f1.z, f1.w);
      int p = l ^ (r & 7);
      *(uint4v*)(&sB[(r * 8 + p) * 8]) = q;
    }
    __syncthreads();
#pragma unroll
    for (int kk = 0; kk < 2; ++kk) {
      int lc = kk * 4 + l4;
      int4v av[8], bv[4];
#pragma unroll
      for (int i = 0; i < 8; ++i) {
        int ar = wr + i * 16 + l15;
        av[i] = *(const int4v*)&sA[(ar * 8 + (lc ^ (ar & 7))) * 8];
      }
#pragma unroll
      for (int j = 0; j < 4; ++j) {
        int br = wc + j * 16 + l15;
        bv[j] = *(const int4v*)&sB[(br * 8 + (lc ^ (br & 7))) * 8];
      }
#pragma unroll
      for (int i = 0; i < 8; ++i)
#pragma unroll
        for (int j = 0; j < 4; ++j) mfma_bf16(acc[i][j], av[i], bv[j]);
    }
    __syncthreads();
  }
  asm volatile("s_nop 7\n\ts_nop 7\n\ts_nop 7" ::: "memory");
  float* cp = Cp + (size_t)z * M * N;
#pragma unroll
  for (int i = 0; i < 8; ++i) {
    int rbase = m0 + wr + i * 16 + l4 * 4;
#pragma unroll
    for (int j = 0; j < 4; ++j) {
      int cc = n0 + wc + j * 16 + l15;
#pragma unroll
      for (int r = 0; r < 4; ++r)
        cp[(size_t)(rbase + r) * N + cc] = acc[i][j][r];
    }
  }
}

// --------------------- splitK reduce + bias + relu -------------------------
__global__ __launch_bounds__(256) void reduce_bias_act(
    const float* __restrict__ parts, const float* __restrict__ bias,
    int MN, int nmask, int nz, unsigned short* __restrict__ out_bf,
    float* __restrict__ out_f) {
  int idx = blockIdx.x * 256 + threadIdx.x;
  if (idx >= MN) return;
  float s = 0.f;
  for (int z = 0; z < nz; ++z) s += parts[(size_t)z * MN + idx];
  s += bias[idx & nmask];
  s = fmaxf(s, 0.f);
  if (out_bf) out_bf[idx] = f32_bf16(s);
  else out_f[idx] = s;
}

// ------------------------------ fc2 + sigmoid ------------------------------
__global__ __launch_bounds__(256) void fc2_kernel(
    const float* __restrict__ h2, const float* __restrict__ w,
    const float* __restrict__ b, float* __restrict__ out) {
  int wave = threadIdx.x >> 6, lane = threadIdx.x & 63;
  int row = blockIdx.x * 4 + wave;
  const float4* hp = (const float4*)(h2 + (size_t)row * 512);
  const float4* wp = (const float4*)w;
  int i0 = lane * 2;
  float4 a0 = hp[i0], a1 = hp[i0 + 1];
  float4 w0 = wp[i0], w1 = wp[i0 + 1];
  float s = a0.x * w0.x + a0.y * w0.y + a0.z * w0.z + a0.w * w0.w +
            a1.x * w1.x + a1.y * w1.y + a1.z * w1.z + a1.w * w1.w;
#pragma unroll
  for (int off = 32; off > 0; off >>= 1) s += __shfl_down(s, off);
  if (lane == 0) out[row] = 1.f / (1.f + expf(-(s + b[0])));
}

// ---------------------------------------------------------------------------
extern "C" void kernel_launch(void* const* d_in, const int* in_sizes, int n_in,
                              void* d_out, int out_size, void* d_ws, size_t ws_size,
                              hipStream_t stream) {
  const float* x     = (const float*)d_in[0];
  const float* Wb1   = (const float*)d_in[1];
  const float* Wb2   = (const float*)d_in[2];
  const float* se_w1 = (const float*)d_in[3];
  const float* se_w2 = (const float*)d_in[4];
  const float* fc0_w = (const float*)d_in[5];
  const float* fc0_b = (const float*)d_in[6];
  const float* fc1_w = (const float*)d_in[7];
  const float* fc1_b = (const float*)d_in[8];
  const float* fc2_w = (const float*)d_in[9];
  const float* fc2_b = (const float*)d_in[10];
  (void)in_sizes; (void)n_in; (void)out_size; (void)ws_size;

  char* ws = (char*)d_ws;
  float*          scale = (float*)(ws + 0);                   //  128 KB
  float*          t1    = (float*)(ws + 131072);              //  7.75 MB
  float*          t2    = (float*)(ws + 8257536);             //  7.75 MB
  unsigned short* feat  = (unsigned short*)(ws + 16384000);   //  124 MB bf16
  float*          hp    = (float*)(ws + 146407424);           //  64 MB partials
  unsigned short* h1b   = (unsigned short*)(ws + 213516288);  //  2 MB bf16
  float*          h2    = (float*)(ws + 215613440);           //  2 MB
  float*          out   = (float*)d_out;

  se_kernel<<<1024, 256, 0, stream>>>(x, se_w1, se_w2, scale);
  t_kernel<<<dim3(31, 16, 2), 256, 0, stream>>>(x, Wb1, Wb2, scale, t1, t2);
  feat_kernel<<<31744, 256, 0, stream>>>(x, t1, t2, scale, feat);
  // fc0: M=1024 N=1024 K=63488, splitK=16 (kz=3968 = 62 k-tiles), 256 blocks
  gemm_fc0<<<256, 512, 0, stream>>>(feat, fc0_w, hp, 1024, 1024, 63488, 3968);
  reduce_bias_act<<<4096, 256, 0, stream>>>(hp, fc0_b, 1024 * 1024, 1023, 16, h1b, nullptr);
  // fc1: M=1024 N=512 K=1024, splitK=16 (kz=64)
  gemm_bt<<<dim3(4, 4, 16), 256, 0, stream>>>(h1b, fc1_w, hp, 1024, 512, 1024, 64);
  reduce_bias_act<<<2048, 256, 0, stream>>>(hp, fc1_b, 1024 * 512, 511, 16, nullptr, h2);
  fc2_kernel<<<256, 256, 0, stream>>>(h2, fc2_w, fc2_b, out);
}